// Round 1
// baseline (18.532 us; speedup 1.0000x reference)
//
#include <hip/hip_runtime.h>
#include <math.h>

// Problem constants (match reference setup_inputs)
#define BB 32
#define LL 1024
#define PP 8
#define DD 256
#define MARGIN_F 0.01f
// total = B * P * (L - P) = 32 * 8 * 1016
#define TOTAL_PAIRS 260096.0f

// Kernel 1: sim[b,l] = cos(sent[b,l,:], query[b,:])
// One wave (64 lanes) per row; lane i handles 4 contiguous floats (float4).
__global__ __launch_bounds__(256) void sim_kernel(const float* __restrict__ sent,
                                                  const float* __restrict__ query,
                                                  float* __restrict__ sim) {
    const int wave = (blockIdx.x * 256 + threadIdx.x) >> 6;   // row id in [0, B*L)
    const int lane = threadIdx.x & 63;
    const int b = wave >> 10;                                  // L = 1024

    const float4 x = *reinterpret_cast<const float4*>(sent + (size_t)wave * DD + lane * 4);
    const float4 q = *reinterpret_cast<const float4*>(query + (size_t)b * DD + lane * 4);

    float dot = x.x * q.x + x.y * q.y + x.z * q.z + x.w * q.w;
    float nx  = x.x * x.x + x.y * x.y + x.z * x.z + x.w * x.w;
    float nq  = q.x * q.x + q.y * q.y + q.z * q.z + q.w * q.w;

#pragma unroll
    for (int off = 32; off > 0; off >>= 1) {
        dot += __shfl_xor(dot, off, 64);
        nx  += __shfl_xor(nx,  off, 64);
        nq  += __shfl_xor(nq,  off, 64);
    }
    if (lane == 0) {
        const float den = fmaxf(sqrtf(nx), 1e-12f) * fmaxf(sqrtf(nq), 1e-12f);
        sim[wave] = dot / den;
    }
}

// Kernel 2: per-split pairwise hinge sum.
// partial[b] = sum_{j in neg(b)} sum_{p in pos(b)} relu(sim[b,j] - sim[b,p] + margin)
__global__ __launch_bounds__(256) void loss_kernel(const float* __restrict__ sim,
                                                   const int* __restrict__ pos_idx,
                                                   float* __restrict__ partial) {
    const int b = blockIdx.x;
    const int tid = threadIdx.x;

    __shared__ float sp[PP];
    __shared__ int   pidx[PP];
    if (tid < PP) {
        const int idx = pos_idx[b * PP + tid];
        pidx[tid] = idx;
        sp[tid]   = sim[b * LL + idx];
    }
    __syncthreads();

    float acc = 0.0f;
#pragma unroll
    for (int it = 0; it < LL / 256; ++it) {
        const int l = tid + it * 256;
        const float s = sim[b * LL + l];
        bool is_pos = false;
#pragma unroll
        for (int p = 0; p < PP; ++p) is_pos |= (l == pidx[p]);
        if (!is_pos) {
#pragma unroll
            for (int p = 0; p < PP; ++p)
                acc += fmaxf(s - sp[p] + MARGIN_F, 0.0f);
        }
    }

    // wave reduce then cross-wave via LDS
#pragma unroll
    for (int off = 32; off > 0; off >>= 1) acc += __shfl_xor(acc, off, 64);

    __shared__ float wsum[4];
    if ((tid & 63) == 0) wsum[tid >> 6] = acc;
    __syncthreads();
    if (tid == 0) partial[b] = wsum[0] + wsum[1] + wsum[2] + wsum[3];
}

// Kernel 3: final reduce + scale. WRITES out (no accumulation — d_out is not
// re-zeroed between graph replays).
__global__ void final_kernel(const float* __restrict__ partial, float* __restrict__ out) {
    float v = (threadIdx.x < BB) ? partial[threadIdx.x] : 0.0f;
#pragma unroll
    for (int off = 32; off > 0; off >>= 1) v += __shfl_xor(v, off, 64);
    if (threadIdx.x == 0) out[0] = v / TOTAL_PAIRS;
}

extern "C" void kernel_launch(void* const* d_in, const int* in_sizes, int n_in,
                              void* d_out, int out_size, void* d_ws, size_t ws_size,
                              hipStream_t stream) {
    const float* sent  = (const float*)d_in[0];   // [B, L, D] f32
    const float* query = (const float*)d_in[1];   // [B, D]    f32
    const int*   pidx  = (const int*)d_in[2];     // [B, P]    int
    float* out = (float*)d_out;

    float* sim     = (float*)d_ws;                // B*L floats = 128 KiB
    float* partial = sim + BB * LL;               // B floats

    // B*L rows, 4 waves per 256-thread block
    sim_kernel<<<(BB * LL) / 4, 256, 0, stream>>>(sent, query, sim);
    loss_kernel<<<BB, 256, 0, stream>>>(sim, pidx, partial);
    final_kernel<<<1, 64, 0, stream>>>(partial, out);
}